// Round 2
// baseline (68.617 us; speedup 1.0000x reference)
//
#include <hip/hip_runtime.h>
#include <cmath>

// ---------------- problem constants (idx = 0) ----------------
#define S_    80
#define NBAT  16
#define NA_   3
#define NCH_  255          // NB * (NC + 5)
#define NC_   80
#define PLANE (S_ * S_)    // 6400
#define CELLS (NBAT * NA_ * PLANE)   // 307200
#define MAXENT (256 * 15)  // N * 5 offsets * 3 anchors upper bound

__device__ __forceinline__ float sp(float x) {   // softplus, stable
    return fmaxf(x, 0.f) + log1pf(__expf(-fabsf(x)));
}

__device__ __forceinline__ float ciou_f(float x1, float y1, float w1, float h1,
                                        float x2, float y2, float w2, float h2) {
    const float EPS = 1e-7f;
    float b1x1 = x1 - w1 * 0.5f, b1x2 = x1 + w1 * 0.5f;
    float b1y1 = y1 - h1 * 0.5f, b1y2 = y1 + h1 * 0.5f;
    float b2x1 = x2 - w2 * 0.5f, b2x2 = x2 + w2 * 0.5f;
    float b2y1 = y2 - h2 * 0.5f, b2y2 = y2 + h2 * 0.5f;
    float iw = fmaxf(fminf(b1x2, b2x2) - fmaxf(b1x1, b2x1), 0.f);
    float ih = fmaxf(fminf(b1y2, b2y2) - fmaxf(b1y1, b2y1), 0.f);
    float inter = iw * ih;
    float uni = w1 * h1 + w2 * h2 - inter + EPS;
    float iou = inter / uni;
    float cw = fmaxf(b1x2, b2x2) - fminf(b1x1, b2x1);
    float ch = fmaxf(b1y2, b2y2) - fminf(b1y1, b2y1);
    float c2 = cw * cw + ch * ch + EPS;
    float dx = b2x1 + b2x2 - b1x1 - b1x2;
    float dy = b2y1 + b2y2 - b1y1 - b1y2;
    float rho2 = (dx * dx + dy * dy) * 0.25f;
    float da = atanf(w2 / (h2 + EPS)) - atanf(w1 / (h1 + EPS));
    float v = 0.40528473456935109f * da * da;   // 4/pi^2
    float alpha = v / (v - iou + (1.f + EPS));
    return iou - (rho2 / c2 + v * alpha);
}

// ---------------- kernel 1: build dedup'd target-cell list ----------------
__global__ void k_build(const float* __restrict__ tgt, int N,
                        unsigned* __restrict__ flags, int* __restrict__ count,
                        int* __restrict__ lcell, int* __restrict__ lcls,
                        float4* __restrict__ lbox) {
    int n = blockIdx.x * blockDim.x + threadIdx.x;
    if (n >= N) return;
    int b   = (int)tgt[n * 6 + 0];
    int cls = (int)tgt[n * 6 + 1];
    float bx = tgt[n * 6 + 2], by = tgt[n * 6 + 3];
    float bw = tgt[n * 6 + 4], bh = tgt[n * 6 + 5];
    if (b < 0 || b >= NBAT) return;

    // anchors / stride(=8)
    const float ax[3] = {12.f / 8.f, 19.f / 8.f, 40.f / 8.f};
    const float ay[3] = {16.f / 8.f, 36.f / 8.f, 28.f / 8.f};
    float whx = bw * S_, why = bh * S_;
    bool rm[3];
#pragma unroll
    for (int a = 0; a < 3; ++a) {
        float rx = whx / ax[a]; rx = fmaxf(rx, 1.f / rx);
        float ry = why / ay[a]; ry = fmaxf(ry, 1.f / ry);
        rm[a] = fmaxf(rx, ry) < 4.0f;
    }
    float gx = bx * S_, gy = by * S_;
    int ib = (int)floorf(gx), jb = (int)floorf(gy);
    float oi = gx - floorf(gx), oj = gy - floorf(gy);
    bool pos[5];
    pos[0] = true;
    pos[1] = (oi < 0.5f) && (gx > 1.f);
    pos[2] = (oj < 0.5f) && (gy > 1.f);
    pos[3] = (oi > 0.5f) && ((S_ - gx) > 1.f);
    pos[4] = (oj > 0.5f) && ((S_ - gy) > 1.f);
    const int di[5] = {0, -1, 0, 1, 0};
    const int dj[5] = {0, 0, -1, 0, 1};
#pragma unroll
    for (int k = 0; k < 5; ++k) {
        if (!pos[k]) continue;
        int ii = ib + di[k], jj = jb + dj[k];
        if (ii < 0 || ii >= S_ || jj < 0 || jj >= S_) continue;  // ref drops OOB
#pragma unroll
        for (int a = 0; a < 3; ++a) {
            if (!rm[a]) continue;
            int cell = ((b * NA_ + a) * S_ + jj) * S_ + ii;
            unsigned m = 1u << (cell & 31);
            unsigned old = atomicOr(&flags[cell >> 5], m);
            if (!(old & m)) {
                int e = atomicAdd(count, 1);
                lcell[e] = cell;
                lcls[e]  = cls;
                lbox[e]  = make_float4(bx, by, bw, bh);
            }
        }
    }
}

// ---------------- kernel 2: per-masked-cell loss (box, cls, obj-correction) --
__global__ void k_masked(const float* __restrict__ preds,
                         const int* __restrict__ count,
                         const int* __restrict__ lcell,
                         const int* __restrict__ lcls,
                         const float4* __restrict__ lbox,
                         double* __restrict__ sums) {
    int t = blockIdx.x * blockDim.x + threadIdx.x;
    if (t >= *count) return;
    int cell = lcell[t];
    int x = cell % S_;
    int y = (cell / S_) % S_;
    int a = (cell / PLANE) % NA_;
    int b = cell / (PLANE * NA_);
    const float* base = preds + (size_t)(b * NCH_ + a * 85) * PLANE + y * S_ + x;
    float p0 = base[0 * PLANE];
    float p1 = base[1 * PLANE];
    float p2 = base[2 * PLANE];
    float p3 = base[3 * PLANE];
    float po = base[4 * PLANE];

    const float anx[3] = {12.f, 19.f, 40.f};
    const float any_[3] = {16.f, 36.f, 28.f};
    float sx = 1.f / (1.f + __expf(-p0));
    float sy = 1.f / (1.f + __expf(-p1));
    float px = (sx * 2.f - 0.5f + (float)x) * (1.0f / S_);
    float py = (sy * 2.f - 0.5f + (float)y) * (1.0f / S_);
    float pw = __expf(p2) * anx[a] * (1.0f / 640.f);
    float ph = __expf(p3) * any_[a] * (1.0f / 640.f);

    float4 tb = lbox[t];
    float iou = ciou_f(px, py, pw, ph, tb.x, tb.y, tb.z, tb.w);

    int cls = lcls[t];
    float cls_sum = 0.f;
    for (int c = 0; c < NC_; ++c) {
        float xc = base[(5 + c) * PLANE];
        cls_sum += sp(xc);
        if (c == cls) cls_sum -= xc;   // bce(x,1) = softplus(x) - x
    }

    atomicAdd(&sums[1], (double)(1.f - iou));
    atomicAdd(&sums[2], (double)cls_sum);
    float t2 = fmaxf(iou, 0.f);
    atomicAdd(&sums[0], (double)(-t2 * po));   // bce(x,t) = sp(x) - t*x
}

// ---------------- kernel 3: dense softplus(pobj) sum over 3 planes ----------
__global__ void k_obj(const float* __restrict__ preds, double* __restrict__ sums) {
    int tid = blockIdx.x * blockDim.x + threadIdx.x;   // over CELLS/4
    float v = 0.f;
    if (tid < CELLS / 4) {
        int plane = tid / (PLANE / 4);     // 0..47  (= b*3 + a)
        int pos   = tid % (PLANE / 4);
        int a = plane % NA_, b = plane / NA_;
        const float4* p4 = (const float4*)preds;
        float4 q = p4[(size_t)(b * NCH_ + a * 85 + 4) * (PLANE / 4) + pos];
        v = sp(q.x) + sp(q.y) + sp(q.z) + sp(q.w);
    }
#pragma unroll
    for (int o = 32; o > 0; o >>= 1) v += __shfl_xor(v, o, 64);
    __shared__ float wsum[4];
    int lane = threadIdx.x & 63, wid = threadIdx.x >> 6;
    if (lane == 0) wsum[wid] = v;
    __syncthreads();
    if (threadIdx.x == 0) {
        float s = wsum[0] + wsum[1] + wsum[2] + wsum[3];
        atomicAdd(&sums[0], (double)s);
    }
}

// ---------------- kernel 4: finalize ----------------
__global__ void k_final(const double* __restrict__ sums,
                        const int* __restrict__ count,
                        float* __restrict__ out) {
    double nobj  = (double)(*count);
    double denom = fmax(nobj, 1.0);
    double loss_obj = sums[0] / (double)CELLS;
    double loss_box = sums[1] / denom;
    double loss_cls = sums[2] / (denom * (double)NC_);
    double loss = (0.7 * 4.0) * loss_obj + 0.3 * loss_cls + 0.05 * loss_box;
    out[0] = (float)(loss * (double)NBAT);
}

extern "C" void kernel_launch(void* const* d_in, const int* in_sizes, int n_in,
                              void* d_out, int out_size, void* d_ws, size_t ws_size,
                              hipStream_t stream) {
    (void)n_in; (void)out_size; (void)ws_size;
    const float* preds = (const float*)d_in[0];
    const float* tgt   = (const float*)d_in[1];
    int N = in_sizes[1] / 6;

    char* ws = (char*)d_ws;
    double*   sums  = (double*)(ws + 0);        // 3 doubles: obj, box, cls
    int*      count = (int*)(ws + 24);          // dedup'd masked-cell count
    unsigned* flags = (unsigned*)(ws + 64);     // CELLS/32 = 9600 words
    int*      lcell = (int*)(ws + 38464);
    int*      lcls  = (int*)(ws + 38464 + MAXENT * 4);
    float4*   lbox  = (float4*)(ws + 38464 + MAXENT * 8);   // 16B aligned

    hipMemsetAsync(ws, 0, 38464, stream);  // sums + count + flags

    k_build<<<(N + 63) / 64, 64, 0, stream>>>(tgt, N, flags, count, lcell, lcls, lbox);
    k_masked<<<(MAXENT + 63) / 64, 64, 0, stream>>>(preds, count, lcell, lcls, lbox, sums);
    k_obj<<<(CELLS / 4 + 255) / 256, 256, 0, stream>>>(preds, sums);
    k_final<<<1, 1, 0, stream>>>(sums, count, (float*)d_out);
}

// Round 3
// 35.935 us; speedup vs baseline: 1.9095x; 1.9095x over previous
//
#include <hip/hip_runtime.h>
#include <cmath>

// ---------------- problem constants (idx = 0) ----------------
#define S_    80
#define NBAT  16
#define NA_   3
#define NCH_  255          // NB * (NC + 5)
#define NC_   80
#define PLANE (S_ * S_)    // 6400
#define CELLS (NBAT * NA_ * PLANE)   // 307200
#define MAXENT (256 * 15)  // N * 5 offsets * 3 anchors upper bound
#define WPB   4            // waves per block in k_masked
#define MBLK  (MAXENT / WPB)          // 960 blocks
#define OBLK  ((CELLS / 4 + 255) / 256) // 300 blocks for k_obj

__device__ __forceinline__ float sp(float x) {   // softplus, stable
    return fmaxf(x, 0.f) + log1pf(__expf(-fabsf(x)));
}

__device__ __forceinline__ float ciou_f(float x1, float y1, float w1, float h1,
                                        float x2, float y2, float w2, float h2) {
    const float EPS = 1e-7f;
    float b1x1 = x1 - w1 * 0.5f, b1x2 = x1 + w1 * 0.5f;
    float b1y1 = y1 - h1 * 0.5f, b1y2 = y1 + h1 * 0.5f;
    float b2x1 = x2 - w2 * 0.5f, b2x2 = x2 + w2 * 0.5f;
    float b2y1 = y2 - h2 * 0.5f, b2y2 = y2 + h2 * 0.5f;
    float iw = fmaxf(fminf(b1x2, b2x2) - fmaxf(b1x1, b2x1), 0.f);
    float ih = fmaxf(fminf(b1y2, b2y2) - fmaxf(b1y1, b2y1), 0.f);
    float inter = iw * ih;
    float uni = w1 * h1 + w2 * h2 - inter + EPS;
    float iou = inter / uni;
    float cw = fmaxf(b1x2, b2x2) - fminf(b1x1, b2x1);
    float ch = fmaxf(b1y2, b2y2) - fminf(b1y1, b2y1);
    float c2 = cw * cw + ch * ch + EPS;
    float dx = b2x1 + b2x2 - b1x1 - b1x2;
    float dy = b2y1 + b2y2 - b1y1 - b1y2;
    float rho2 = (dx * dx + dy * dy) * 0.25f;
    float da = atanf(w2 / (h2 + EPS)) - atanf(w1 / (h1 + EPS));
    float v = 0.40528473456935109f * da * da;   // 4/pi^2
    float alpha = v / (v - iou + (1.f + EPS));
    return iou - (rho2 / c2 + v * alpha);
}

// ---------------- kernel 1: build dedup'd target-cell list ----------------
// one wave per 64 targets; count-atomic aggregated per wave (ballot+prefix)
__global__ void k_build(const float* __restrict__ tgt, int N,
                        unsigned* __restrict__ flags, int* __restrict__ count,
                        int* __restrict__ lcell, int* __restrict__ lcls,
                        float4* __restrict__ lbox) {
    int lane = threadIdx.x & 63;
    int n = blockIdx.x * 64 + lane;
    bool active = (n < N);
    int b = 0, cls = 0, ib = 0, jb = 0;
    float bx = 0.f, by = 0.f, bw = 0.f, bh = 0.f;
    bool rm[3] = {false, false, false};
    bool pos[5] = {false, false, false, false, false};
    if (active) {
        b   = (int)tgt[n * 6 + 0];
        cls = (int)tgt[n * 6 + 1];
        bx = tgt[n * 6 + 2]; by = tgt[n * 6 + 3];
        bw = tgt[n * 6 + 4]; bh = tgt[n * 6 + 5];
        if (b < 0 || b >= NBAT) active = false;
    }
    if (active) {
        const float ax[3] = {12.f / 8.f, 19.f / 8.f, 40.f / 8.f};
        const float ay[3] = {16.f / 8.f, 36.f / 8.f, 28.f / 8.f};
        float whx = bw * S_, why = bh * S_;
#pragma unroll
        for (int a = 0; a < 3; ++a) {
            float rx = whx / ax[a]; rx = fmaxf(rx, 1.f / rx);
            float ry = why / ay[a]; ry = fmaxf(ry, 1.f / ry);
            rm[a] = fmaxf(rx, ry) < 4.0f;
        }
        float gx = bx * S_, gy = by * S_;
        ib = (int)floorf(gx); jb = (int)floorf(gy);
        float oi = gx - floorf(gx), oj = gy - floorf(gy);
        pos[0] = true;
        pos[1] = (oi < 0.5f) && (gx > 1.f);
        pos[2] = (oj < 0.5f) && (gy > 1.f);
        pos[3] = (oi > 0.5f) && ((S_ - gx) > 1.f);
        pos[4] = (oj > 0.5f) && ((S_ - gy) > 1.f);
    }
    const int di[5] = {0, -1, 0, 1, 0};
    const int dj[5] = {0, 0, -1, 0, 1};
#pragma unroll
    for (int k = 0; k < 5; ++k) {
#pragma unroll
        for (int a = 0; a < 3; ++a) {
            bool want = false;
            int cell = 0;
            if (active && pos[k] && rm[a]) {
                int ii = ib + di[k], jj = jb + dj[k];
                if (ii >= 0 && ii < S_ && jj >= 0 && jj < S_) {  // ref drops OOB
                    cell = ((b * NA_ + a) * S_ + jj) * S_ + ii;
                    unsigned m = 1u << (cell & 31);
                    unsigned old = atomicOr(&flags[cell >> 5], m);
                    want = !(old & m);
                }
            }
            unsigned long long mask = __ballot(want);
            if (mask) {
                int leader = __ffsll((unsigned long long)mask) - 1;
                int prefix = __popcll(mask & ((1ull << lane) - 1ull));
                int base = 0;
                if (lane == leader) base = atomicAdd(count, __popcll(mask));
                base = __shfl(base, leader, 64);
                if (want) {
                    int e = base + prefix;
                    lcell[e] = cell;
                    lcls[e]  = cls;
                    lbox[e]  = make_float4(bx, by, bw, bh);
                }
            }
        }
    }
}

// ---------------- kernel 2: one WAVE per masked cell --------------------
// lane l loads channel l (and 64+l for l<21): all 85 scattered lines per
// cell issue in parallel; class BCE reduced via shfl_xor; box via shfl.
__global__ void k_masked(const float* __restrict__ preds,
                         const int* __restrict__ count,
                         const int* __restrict__ lcell,
                         const int* __restrict__ lcls,
                         const float4* __restrict__ lbox,
                         double* __restrict__ partials) {
    int wid = threadIdx.x >> 6, lane = threadIdx.x & 63;
    int t = blockIdx.x * WPB + wid;
    double obj_c = 0.0, box_t = 0.0, cls_s = 0.0;
    if (t < *count) {
        int cell = lcell[t];
        int x = cell % S_;
        int y = (cell / S_) % S_;
        int a = (cell / PLANE) % NA_;
        int b = cell / (PLANE * NA_);
        const float* base = preds + (size_t)(b * NCH_ + a * 85) * PLANE + y * S_ + x;
        float v0 = base[lane * PLANE];
        float v1 = (lane < 21) ? base[(64 + lane) * PLANE] : 0.f;
        int clsch = 5 + lcls[t];
        float cs = 0.f;
        if (lane >= 5) { cs += sp(v0); if (lane == clsch) cs -= v0; }
        if (lane < 21) { cs += sp(v1); if (64 + lane == clsch) cs -= v1; }
#pragma unroll
        for (int o = 32; o > 0; o >>= 1) cs += __shfl_xor(cs, o, 64);
        float p0 = __shfl(v0, 0, 64);
        float p1 = __shfl(v0, 1, 64);
        float p2 = __shfl(v0, 2, 64);
        float p3 = __shfl(v0, 3, 64);
        float po = __shfl(v0, 4, 64);

        const float anx[3]  = {12.f, 19.f, 40.f};
        const float any_[3] = {16.f, 36.f, 28.f};
        float sx = 1.f / (1.f + __expf(-p0));
        float sy = 1.f / (1.f + __expf(-p1));
        float px = (sx * 2.f - 0.5f + (float)x) * (1.0f / S_);
        float py = (sy * 2.f - 0.5f + (float)y) * (1.0f / S_);
        float pw = __expf(p2) * anx[a] * (1.0f / 640.f);
        float ph = __expf(p3) * any_[a] * (1.0f / 640.f);

        float4 tb = lbox[t];
        float iou = ciou_f(px, py, pw, ph, tb.x, tb.y, tb.z, tb.w);
        if (lane == 0) {
            box_t = (double)(1.f - iou);
            cls_s = (double)cs;
            obj_c = (double)(-fmaxf(iou, 0.f) * po);   // bce(x,t) = sp(x) - t*x
        }
    }
    __shared__ double sm[WPB][3];
    if (lane == 0) { sm[wid][0] = obj_c; sm[wid][1] = box_t; sm[wid][2] = cls_s; }
    __syncthreads();
    if (threadIdx.x == 0) {
        double o = 0, bx = 0, cl = 0;
#pragma unroll
        for (int w = 0; w < WPB; ++w) { o += sm[w][0]; bx += sm[w][1]; cl += sm[w][2]; }
        double* p = partials + (size_t)blockIdx.x * 3;
        p[0] = o; p[1] = bx; p[2] = cl;
    }
}

// ---------------- kernel 3: dense softplus(pobj) sum over 3 planes ----------
__global__ void k_obj(const float* __restrict__ preds, double* __restrict__ pobj_part) {
    int tid = blockIdx.x * blockDim.x + threadIdx.x;   // over CELLS/4
    float v = 0.f;
    if (tid < CELLS / 4) {
        int plane = tid / (PLANE / 4);     // 0..47  (= b*3 + a)
        int pos   = tid % (PLANE / 4);
        int a = plane % NA_, b = plane / NA_;
        const float4* p4 = (const float4*)preds;
        float4 q = p4[(size_t)(b * NCH_ + a * 85 + 4) * (PLANE / 4) + pos];
        v = sp(q.x) + sp(q.y) + sp(q.z) + sp(q.w);
    }
#pragma unroll
    for (int o = 32; o > 0; o >>= 1) v += __shfl_xor(v, o, 64);
    __shared__ float wsum[4];
    int lane = threadIdx.x & 63, wid = threadIdx.x >> 6;
    if (lane == 0) wsum[wid] = v;
    __syncthreads();
    if (threadIdx.x == 0)
        pobj_part[blockIdx.x] = (double)(wsum[0] + wsum[1] + wsum[2] + wsum[3]);
}

// ---------------- kernel 4: deterministic final reduce + scalar -------------
__global__ void k_final(const double* __restrict__ partials,
                        const double* __restrict__ pobj_part,
                        const int* __restrict__ count,
                        float* __restrict__ out) {
    __shared__ double so[256], sb[256], sc[256];
    int tid = threadIdx.x;
    double o = 0, b = 0, c = 0;
    for (int i = tid; i < MBLK; i += 256) {
        o += partials[(size_t)i * 3];
        b += partials[(size_t)i * 3 + 1];
        c += partials[(size_t)i * 3 + 2];
    }
    for (int i = tid; i < OBLK; i += 256) o += pobj_part[i];
    so[tid] = o; sb[tid] = b; sc[tid] = c;
    __syncthreads();
    for (int s = 128; s > 0; s >>= 1) {
        if (tid < s) { so[tid] += so[tid + s]; sb[tid] += sb[tid + s]; sc[tid] += sc[tid + s]; }
        __syncthreads();
    }
    if (tid == 0) {
        double nobj  = (double)(*count);
        double denom = fmax(nobj, 1.0);
        double loss_obj = so[0] / (double)CELLS;
        double loss_box = sb[0] / denom;
        double loss_cls = sc[0] / (denom * (double)NC_);
        double loss = (0.7 * 4.0) * loss_obj + 0.3 * loss_cls + 0.05 * loss_box;
        out[0] = (float)(loss * (double)NBAT);
    }
}

extern "C" void kernel_launch(void* const* d_in, const int* in_sizes, int n_in,
                              void* d_out, int out_size, void* d_ws, size_t ws_size,
                              hipStream_t stream) {
    (void)n_in; (void)out_size; (void)ws_size;
    const float* preds = (const float*)d_in[0];
    const float* tgt   = (const float*)d_in[1];
    int N = in_sizes[1] / 6;

    char* ws = (char*)d_ws;
    int*      count = (int*)(ws + 0);
    unsigned* flags = (unsigned*)(ws + 64);                 // 9600 words
    int*      lcell = (int*)(ws + 38464);                   // MAXENT ints
    int*      lcls  = (int*)(ws + 38464 + MAXENT * 4);
    float4*   lbox  = (float4*)(ws + 38464 + MAXENT * 8);   // 16B aligned
    double*   partials  = (double*)(ws + 130624);           // MBLK*3 doubles
    double*   pobj_part = (double*)(ws + 153664);           // OBLK doubles

    hipMemsetAsync(ws, 0, 38464, stream);  // count + flags

    k_build<<<(N + 63) / 64, 64, 0, stream>>>(tgt, N, flags, count, lcell, lcls, lbox);
    k_masked<<<MBLK, WPB * 64, 0, stream>>>(preds, count, lcell, lcls, lbox, partials);
    k_obj<<<OBLK, 256, 0, stream>>>(preds, pobj_part);
    k_final<<<1, 256, 0, stream>>>(partials, pobj_part, count, (float*)d_out);
}